// Round 3
// baseline (288.761 us; speedup 1.0000x reference)
//
#include <hip/hip_runtime.h>
#include <stdint.h>

typedef __bf16 bf16;
typedef __bf16 bf16x4 __attribute__((ext_vector_type(4)));
typedef __bf16 bf16x8 __attribute__((ext_vector_type(8)));
typedef float f32x4 __attribute__((ext_vector_type(4)));

// --------------------------------------------- fused cast + transpose for x
__global__ __launch_bounds__(256) void k_castT(const float* __restrict__ src,
                                               bf16* __restrict__ dst,
                                               bf16* __restrict__ dstT) {
  const size_t bo = (size_t)blockIdx.z * 4096 * 1024;
  const float* s = src + bo;
  bf16* d = dst + bo;
  bf16* dT = dstT + bo;
  __shared__ float tile[64][65];
  const int r0 = blockIdx.y * 64, c0 = blockIdx.x * 64;
  const int tr = threadIdx.x >> 6, tc = threadIdx.x & 63;
#pragma unroll
  for (int i = 0; i < 16; ++i) {
    const int r = i * 4 + tr;
    const float v = s[(size_t)(r0 + r) * 1024 + (c0 + tc)];
    tile[r][tc] = v;
    d[(size_t)(r0 + r) * 1024 + (c0 + tc)] = (bf16)v;
  }
  __syncthreads();
#pragma unroll
  for (int i = 0; i < 16; ++i) {
    const int r = i * 4 + tr;
    dT[(size_t)(c0 + r) * 4096 + (r0 + tc)] = (bf16)tile[tc][r];
  }
}

// ------------------------------------------------------- transpose + cast bf16
struct TP4 { const float* src[4]; bf16* dst[4]; };

__global__ __launch_bounds__(256) void k_tcast(TP4 args, int R, int C) {
  const float* __restrict__ src = args.src[blockIdx.z];
  bf16* __restrict__ dst = args.dst[blockIdx.z];
  __shared__ float tile[64][65];
  const int r0 = blockIdx.y * 64, c0 = blockIdx.x * 64;
  const int tr = threadIdx.x >> 6, tc = threadIdx.x & 63;
#pragma unroll
  for (int i = 0; i < 16; ++i) {
    int r = i * 4 + tr;
    tile[r][tc] = src[(size_t)(r0 + r) * C + (c0 + tc)];
  }
  __syncthreads();
#pragma unroll
  for (int i = 0; i < 16; ++i) {
    int r = i * 4 + tr;
    dst[(size_t)(c0 + r) * R + (r0 + tc)] = (bf16)tile[tc][r];
  }
}

// ---------------------------------------------------------------- NT bf16 GEMM
// C[m][n] = sum_k A[m][k] * Bt[n][k].  128x128 tile, BK=32, 4 waves (2x2).
// zmod/kOff: split-K; mbSplit: block-diag B select; mbT: blocks mb>=mbT write
// their output TRANSPOSED into Ct (Ct[col][row-mbT*128], leading dim ldct).
#define GLL(gp, lp)                                              \
  __builtin_amdgcn_global_load_lds(                              \
      (const __attribute__((address_space(1))) void*)(gp),       \
      (__attribute__((address_space(3))) void*)(lp), 16, 0, 0)

template <typename CT>
__global__ __launch_bounds__(256) void k_gemm_nt(
    const bf16* __restrict__ A, const bf16* __restrict__ Bt,
    const bf16* __restrict__ Bt2, CT* __restrict__ C,
    int lda, int ldb, int ldc, int Kd, long sA, long sB, long sC,
    int zmod, long kOff, int mbSplit, CT* __restrict__ Ct, long sCt, int ldct,
    int mbT) {
  int zb = blockIdx.z, kc = 0;
  if (zmod > 1) { zb = blockIdx.z / zmod; kc = blockIdx.z % zmod; }
  const int mb = blockIdx.x, nb = blockIdx.y;
  A += (long)zb * sA + (long)kc * kOff;
  const bf16* Bsel = (mb < mbSplit) ? Bt : Bt2;
  Bsel += (long)zb * sB + (long)kc * kOff;
  C += (long)blockIdx.z * sC;
  Ct += (long)blockIdx.z * sCt;

  __shared__ bf16 As[2][128 * 32];
  __shared__ bf16 Bs[2][128 * 32];
  const int tid = threadIdx.x, lane = tid & 63, wid = tid >> 6;
  const int wr = wid >> 1, wc = wid & 1;
  const int srow = lane >> 2;
  const int skk = (((lane & 3) ^ ((srow >> 1) & 3)) << 3);

  f32x4 acc[4][4] = {};
  const bf16* Abase = A + (long)mb * 128 * lda;
  const bf16* Bbase = Bsel + (long)nb * 128 * ldb;

  auto stage = [&](int buf, int k0) {
#pragma unroll
    for (int i = 0; i < 2; ++i) {
      const int ch = wid * 2 + i;
      const int row = ch * 16 + srow;
      GLL(Abase + (long)row * lda + k0 + skk, &As[buf][ch * 512]);
      GLL(Bbase + (long)row * ldb + k0 + skk, &Bs[buf][ch * 512]);
    }
  };

  stage(0, 0);
  const int nk = Kd >> 5;
  for (int kt = 0; kt < nk; ++kt) {
    const int cur = kt & 1;
    if (kt + 1 < nk) stage(cur ^ 1, (kt + 1) << 5);
    __syncthreads();
    const int slot = lane >> 4;
    bf16x8 af[4], bb[4];
#pragma unroll
    for (int i = 0; i < 4; ++i) {
      const int r = wr * 64 + i * 16 + (lane & 15);
      af[i] = *reinterpret_cast<const bf16x8*>(
          reinterpret_cast<const char*>(As[cur]) + r * 64 +
          ((slot ^ ((r >> 1) & 3)) << 4));
      const int c = wc * 64 + i * 16 + (lane & 15);
      bb[i] = *reinterpret_cast<const bf16x8*>(
          reinterpret_cast<const char*>(Bs[cur]) + c * 64 +
          ((slot ^ ((c >> 1) & 3)) << 4));
    }
#pragma unroll
    for (int i = 0; i < 4; ++i)
#pragma unroll
      for (int j = 0; j < 4; ++j)
        acc[i][j] =
            __builtin_amdgcn_mfma_f32_16x16x32_bf16(af[i], bb[j], acc[i][j], 0, 0, 0);
    __syncthreads();
  }

  const long row0 = (long)mb * 128 + wr * 64 + ((lane >> 4) << 2);
  const int col0 = nb * 128 + wc * 64 + (lane & 15);
  if (mb >= mbT) {
    const long r0 = row0 - (long)mbT * 128;
#pragma unroll
    for (int i = 0; i < 4; ++i)
#pragma unroll
      for (int j = 0; j < 4; ++j)
#pragma unroll
        for (int r = 0; r < 4; ++r)
          Ct[(long)(col0 + j * 16) * ldct + (r0 + i * 16 + r)] = (CT)acc[i][j][r];
  } else {
#pragma unroll
    for (int i = 0; i < 4; ++i)
#pragma unroll
      for (int j = 0; j < 4; ++j)
#pragma unroll
        for (int r = 0; r < 4; ++r)
          C[(row0 + i * 16 + r) * ldc + (col0 + j * 16)] = (CT)acc[i][j][r];
  }
}

// ---------------------------------------------- split-K partial reduce (4 -> 1)
__global__ __launch_bounds__(256) void k_red4(const float* __restrict__ p,
                                              bf16* __restrict__ out) {
  const int i = blockIdx.x * 256 + threadIdx.x;
  const int SL = 512 * 1024;
  const int b = (i * 4) / SL;
  const int e = (i * 4) % SL;
  const float* base = p + (size_t)b * 4 * SL + e;
  float4 s0 = *reinterpret_cast<const float4*>(base);
  float4 s1 = *reinterpret_cast<const float4*>(base + SL);
  float4 s2 = *reinterpret_cast<const float4*>(base + 2 * SL);
  float4 s3 = *reinterpret_cast<const float4*>(base + 3 * SL);
  bf16x4 o;
  o[0] = (bf16)(s0.x + s1.x + s2.x + s3.x);
  o[1] = (bf16)(s0.y + s1.y + s2.y + s3.y);
  o[2] = (bf16)(s0.z + s1.z + s2.z + s3.z);
  o[3] = (bf16)(s0.w + s1.w + s2.w + s3.w);
  *reinterpret_cast<bf16x4*>(out + (size_t)b * SL + e) = o;
}

// ------------------------------------------------------------- fused attention
// grid (16 l-tiles, 16 heads, 4 batch), 512 thr = 8 waves; 256 Q-rows/block.
// Each wave: 32 rows in 2 chunks of 16.  LDS 128KB:
//   Ks [256][64] swz (32K) | Vs=V^T [64][256] swz (32K) | Ps 8 x [16][256] (64K)
__global__ __launch_bounds__(512, 2) void k_attn(const bf16* __restrict__ q,
                                                 const bf16* __restrict__ kc,
                                                 const bf16* __restrict__ vT,
                                                 bf16* __restrict__ aout) {
  const int lt = blockIdx.x, h = blockIdx.y, b = blockIdx.z;
  const int tid = threadIdx.x, lane = tid & 63, wid = tid >> 6;
  __shared__ bf16 smem[65536];  // 128 KB
  bf16* Ks = smem;
  bf16* Vs = smem + 16384;
  bf16* Ps = smem + 32768 + wid * 4096;

  // stage K [256 k][64 d]: 2048 x 16B chunks, swizzled slot = s ^ (k&7)
  const bf16* kb = kc + ((long)b * 256) * 1024 + h * 64;
#pragma unroll
  for (int it = 0; it < 4; ++it) {
    const int lin = it * 512 + tid;
    const int k = lin >> 3, s = lin & 7;
    bf16x8 v = *reinterpret_cast<const bf16x8*>(kb + (long)k * 1024 + s * 8);
    *reinterpret_cast<bf16x8*>(reinterpret_cast<char*>(Ks) + k * 128 +
                               ((s ^ (k & 7)) << 4)) = v;
  }
  // stage V^T [64 d][256 k]: vectorized, swizzled slot = s ^ (d&7)
  const bf16* vb = vT + (long)b * 1024 * 256 + (long)h * 64 * 256;
#pragma unroll
  for (int it = 0; it < 4; ++it) {
    const int lin = it * 512 + tid;
    const int d = lin >> 5, s = lin & 31;
    bf16x8 v = *reinterpret_cast<const bf16x8*>(vb + (long)d * 256 + s * 8);
    *reinterpret_cast<bf16x8*>(reinterpret_cast<char*>(Vs) + d * 512 +
                               ((s ^ (d & 7)) << 4)) = v;
  }
  __syncthreads();

  for (int c = 0; c < 2; ++c) {
    const long qrow = (long)b * 4096 + lt * 256 + wid * 32 + c * 16;
    const bf16* qb = q + (qrow + (lane & 15)) * 1024 + h * 64;
    bf16x8 qf[2];
#pragma unroll
    for (int ks = 0; ks < 2; ++ks)
      qf[ks] = *reinterpret_cast<const bf16x8*>(qb + ks * 32 + ((lane >> 4) << 3));

    // QK^T: logits [16 rows][256]
    f32x4 ln[16] = {};
#pragma unroll
    for (int ks = 0; ks < 2; ++ks) {
      const int slot = ks * 4 + (lane >> 4);
#pragma unroll
      for (int nf = 0; nf < 16; ++nf) {
        const int kcol = nf * 16 + (lane & 15);
        bf16x8 kf = *reinterpret_cast<const bf16x8*>(
            reinterpret_cast<const char*>(Ks) + kcol * 128 +
            ((slot ^ (kcol & 7)) << 4));
        ln[nf] = __builtin_amdgcn_mfma_f32_16x16x32_bf16(qf[ks], kf, ln[nf], 0, 0, 0);
      }
    }

    // softmax (scale 1/8); lane holds rows (lane>>4)*4+r, cols lane&15+16*nf
#pragma unroll
    for (int r = 0; r < 4; ++r) {
      float m = -1e30f;
#pragma unroll
      for (int nf = 0; nf < 16; ++nf) m = fmaxf(m, ln[nf][r]);
#pragma unroll
      for (int s = 1; s < 16; s <<= 1) m = fmaxf(m, __shfl_xor(m, s, 64));
      float sum = 0.f;
#pragma unroll
      for (int nf = 0; nf < 16; ++nf) {
        float p = __expf((ln[nf][r] - m) * 0.125f);
        ln[nf][r] = p;
        sum += p;
      }
#pragma unroll
      for (int s = 1; s < 16; s <<= 1) sum += __shfl_xor(sum, s, 64);
      const float inv = 1.f / sum;
      const int row = ((lane >> 4) << 2) + r;
#pragma unroll
      for (int nf = 0; nf < 16; ++nf) {
        const int col = nf * 16 + (lane & 15);
        *reinterpret_cast<bf16*>(reinterpret_cast<char*>(Ps) + row * 512 +
                                 ((col * 2) ^ ((row & 7) << 4))) =
            (bf16)(ln[nf][r] * inv);
      }
    }

    // PV: out[16][64] = P[16][256] @ V[256][64]
    f32x4 oacc[4] = {};
#pragma unroll
    for (int ks = 0; ks < 8; ++ks) {
      const int arow = lane & 15;
      const int ak = ks * 32 + ((lane >> 4) << 3);
      bf16x8 pa = *reinterpret_cast<const bf16x8*>(
          reinterpret_cast<const char*>(Ps) + arow * 512 +
          ((ak * 2) ^ ((arow & 7) << 4)));
      const int slot = ks * 4 + (lane >> 4);
#pragma unroll
      for (int nf = 0; nf < 4; ++nf) {
        const int d2 = nf * 16 + (lane & 15);
        bf16x8 vv = *reinterpret_cast<const bf16x8*>(
            reinterpret_cast<const char*>(Vs) + d2 * 512 +
            ((slot ^ (d2 & 7)) << 4));
        oacc[nf] = __builtin_amdgcn_mfma_f32_16x16x32_bf16(pa, vv, oacc[nf], 0, 0, 0);
      }
    }

    bf16* ob = aout + (qrow + ((lane >> 4) << 2)) * 1024 + h * 64 + (lane & 15);
#pragma unroll
    for (int nf = 0; nf < 4; ++nf)
#pragma unroll
      for (int r = 0; r < 4; ++r) ob[(long)r * 1024 + nf * 16] = (bf16)oacc[nf][r];
  }
}

// --------------------------------------------------------------------- launch
extern "C" void kernel_launch(void* const* d_in, const int* in_sizes, int n_in,
                              void* d_out, int out_size, void* d_ws, size_t ws_size,
                              hipStream_t stream) {
  const float* x  = (const float*)d_in[0];
  const float* Wq = (const float*)d_in[1];
  const float* Wk = (const float*)d_in[2];
  const float* Wv = (const float*)d_in[3];
  const float* Wo = (const float*)d_in[4];
  const float* Pk = (const float*)d_in[5];
  const float* Pv = (const float*)d_in[6];
  char* ws = (char*)d_ws;
  const long MB = 1024L * 1024;
  bf16* xbf = (bf16*)ws;               // 32 MB (dead after Q gemm -> aout)
  bf16* XT  = (bf16*)(ws + 32 * MB);   // 32 MB x^T per batch
  bf16* WqT = (bf16*)(ws + 64 * MB);
  bf16* WkT = (bf16*)(ws + 66 * MB);
  bf16* WvT = (bf16*)(ws + 68 * MB);
  bf16* WoT = (bf16*)(ws + 70 * MB);
  bf16* PT  = (bf16*)(ws + 72 * MB);   // [Pk^T ; Pv^T] = [512][4096]
  float* XCp = (float*)(ws + 76 * MB); // 32 MB fp32 split-K partials
  bf16* qbf = (bf16*)(ws + 76 * MB);   // 32 MB (after reduce)
  bf16* XC  = (bf16*)(ws + 108 * MB);  // 4 MB [4][512][1024]
  bf16* kcb = (bf16*)(ws + 112 * MB);  // 2 MB [4][256][1024]
  bf16* vcT = (bf16*)(ws + 114 * MB);  // 2 MB [4][1024][256]
  bf16* aout = xbf;
  const int BIG = 1 << 30;
  (void)in_sizes; (void)n_in; (void)out_size; (void)ws_size;

  // 1) x -> xbf (bf16) and XT (x^T per batch), one pass
  k_castT<<<dim3(16, 64, 4), 256, 0, stream>>>(x, xbf, XT);

  // 2) W transposes
  TP4 tw = {{Wq, Wk, Wv, Wo}, {WqT, WkT, WvT, WoT}};
  k_tcast<<<dim3(16, 16, 4), 256, 0, stream>>>(tw, 1024, 1024);

  // 3) P transposes
  TP4 tp = {{Pk, Pv, Pk, Pk}, {PT, PT + 256 * 4096, PT, PT}};
  k_tcast<<<dim3(4, 64, 2), 256, 0, stream>>>(tp, 4096, 256);

  // 4) XC split-K partials + reduce
  k_gemm_nt<float><<<dim3(4, 8, 16), 256, 0, stream>>>(
      PT, XT, XT, XCp, 4096, 4096, 1024, 1024, 0, 1024L * 4096, 512L * 1024, 4, 1024,
      BIG, XCp, 0, 1024, BIG);
  k_red4<<<dim3(2048), 256, 0, stream>>>(XCp, XC);

  // 5) kc = XCk@Wk (normal) ; vcT = (XCv@Wv)^T (transposed epilogue)
  k_gemm_nt<bf16><<<dim3(4, 8, 4), 256, 0, stream>>>(
      XC, WkT, WvT, kcb, 1024, 1024, 1024, 1024, 512L * 1024, 0, 256L * 1024, 1, 0, 2,
      vcT, 1024L * 256, 256, 2);

  // 6) Q = x @ Wq
  k_gemm_nt<bf16><<<dim3(128, 8, 1), 256, 0, stream>>>(
      xbf, WqT, WqT, qbf, 1024, 1024, 1024, 1024, 0, 0, 0, 1, 0, BIG, qbf, 0, 1024,
      BIG);

  // 7) attention
  k_attn<<<dim3(16, 16, 4), 512, 0, stream>>>(qbf, kcb, vcT, aout);

  // 8) out = aout @ Wo (fp32 out)
  k_gemm_nt<float><<<dim3(128, 8, 1), 256, 0, stream>>>(
      aout, WoT, WoT, (float*)d_out, 1024, 1024, 1024, 1024, 0, 0, 0, 1, 0, BIG,
      (float*)d_out, 0, 1024, BIG);
}

// Round 4
// 224.953 us; speedup vs baseline: 1.2836x; 1.2836x over previous
//
#include <hip/hip_runtime.h>
#include <stdint.h>

typedef __bf16 bf16;
typedef __bf16 bf16x4 __attribute__((ext_vector_type(4)));
typedef __bf16 bf16x8 __attribute__((ext_vector_type(8)));
typedef float f32x4 __attribute__((ext_vector_type(4)));

// --------------------------------------------- fused cast + transpose for x
__global__ __launch_bounds__(256) void k_castT(const float* __restrict__ src,
                                               bf16* __restrict__ dst,
                                               bf16* __restrict__ dstT) {
  const size_t bo = (size_t)blockIdx.z * 4096 * 1024;
  const float* s = src + bo;
  bf16* d = dst + bo;
  bf16* dT = dstT + bo;
  __shared__ float tile[64][65];
  const int r0 = blockIdx.y * 64, c0 = blockIdx.x * 64;
  const int tr = threadIdx.x >> 6, tc = threadIdx.x & 63;
#pragma unroll
  for (int i = 0; i < 16; ++i) {
    const int r = i * 4 + tr;
    const float v = s[(size_t)(r0 + r) * 1024 + (c0 + tc)];
    tile[r][tc] = v;
    d[(size_t)(r0 + r) * 1024 + (c0 + tc)] = (bf16)v;
  }
  __syncthreads();
#pragma unroll
  for (int i = 0; i < 16; ++i) {
    const int r = i * 4 + tr;
    dT[(size_t)(c0 + r) * 4096 + (r0 + tc)] = (bf16)tile[tc][r];
  }
}

// ------------------------------------------------------- transpose + cast bf16
struct TP4 { const float* src[4]; bf16* dst[4]; };

__global__ __launch_bounds__(256) void k_tcast(TP4 args, int R, int C) {
  const float* __restrict__ src = args.src[blockIdx.z];
  bf16* __restrict__ dst = args.dst[blockIdx.z];
  __shared__ float tile[64][65];
  const int r0 = blockIdx.y * 64, c0 = blockIdx.x * 64;
  const int tr = threadIdx.x >> 6, tc = threadIdx.x & 63;
#pragma unroll
  for (int i = 0; i < 16; ++i) {
    int r = i * 4 + tr;
    tile[r][tc] = src[(size_t)(r0 + r) * C + (c0 + tc)];
  }
  __syncthreads();
#pragma unroll
  for (int i = 0; i < 16; ++i) {
    int r = i * 4 + tr;
    dst[(size_t)(c0 + r) * R + (r0 + tc)] = (bf16)tile[tc][r];
  }
}

// ---------------------------------------------------------------- NT bf16 GEMM
// C[m][n] = sum_k A[m][k] * Bt[n][k].  128x128 tile, BK=32, 4 waves (2x2).
// zmod/kOff: split-K; mbSplit: block-diag B select; mbT: blocks mb>=mbT write
// their output TRANSPOSED into Ct.
#define GLL(gp, lp)                                              \
  __builtin_amdgcn_global_load_lds(                              \
      (const __attribute__((address_space(1))) void*)(gp),       \
      (__attribute__((address_space(3))) void*)(lp), 16, 0, 0)

template <typename CT>
__global__ __launch_bounds__(256) void k_gemm_nt(
    const bf16* __restrict__ A, const bf16* __restrict__ Bt,
    const bf16* __restrict__ Bt2, CT* __restrict__ C,
    int lda, int ldb, int ldc, int Kd, long sA, long sB, long sC,
    int zmod, long kOff, int mbSplit, CT* __restrict__ Ct, long sCt, int ldct,
    int mbT) {
  int zb = blockIdx.z, kc = 0;
  if (zmod > 1) { zb = blockIdx.z / zmod; kc = blockIdx.z % zmod; }
  const int mb = blockIdx.x, nb = blockIdx.y;
  A += (long)zb * sA + (long)kc * kOff;
  const bf16* Bsel = (mb < mbSplit) ? Bt : Bt2;
  Bsel += (long)zb * sB + (long)kc * kOff;
  C += (long)blockIdx.z * sC;
  Ct += (long)blockIdx.z * sCt;

  __shared__ bf16 As[2][128 * 32];
  __shared__ bf16 Bs[2][128 * 32];
  const int tid = threadIdx.x, lane = tid & 63, wid = tid >> 6;
  const int wr = wid >> 1, wc = wid & 1;
  const int srow = lane >> 2;
  const int skk = (((lane & 3) ^ ((srow >> 1) & 3)) << 3);

  f32x4 acc[4][4] = {};
  const bf16* Abase = A + (long)mb * 128 * lda;
  const bf16* Bbase = Bsel + (long)nb * 128 * ldb;

  auto stage = [&](int buf, int k0) {
#pragma unroll
    for (int i = 0; i < 2; ++i) {
      const int ch = wid * 2 + i;
      const int row = ch * 16 + srow;
      GLL(Abase + (long)row * lda + k0 + skk, &As[buf][ch * 512]);
      GLL(Bbase + (long)row * ldb + k0 + skk, &Bs[buf][ch * 512]);
    }
  };

  stage(0, 0);
  const int nk = Kd >> 5;
  for (int kt = 0; kt < nk; ++kt) {
    const int cur = kt & 1;
    if (kt + 1 < nk) stage(cur ^ 1, (kt + 1) << 5);
    __syncthreads();
    const int slot = lane >> 4;
    bf16x8 af[4], bb[4];
#pragma unroll
    for (int i = 0; i < 4; ++i) {
      const int r = wr * 64 + i * 16 + (lane & 15);
      af[i] = *reinterpret_cast<const bf16x8*>(
          reinterpret_cast<const char*>(As[cur]) + r * 64 +
          ((slot ^ ((r >> 1) & 3)) << 4));
      const int c = wc * 64 + i * 16 + (lane & 15);
      bb[i] = *reinterpret_cast<const bf16x8*>(
          reinterpret_cast<const char*>(Bs[cur]) + c * 64 +
          ((slot ^ ((c >> 1) & 3)) << 4));
    }
#pragma unroll
    for (int i = 0; i < 4; ++i)
#pragma unroll
      for (int j = 0; j < 4; ++j)
        acc[i][j] =
            __builtin_amdgcn_mfma_f32_16x16x32_bf16(af[i], bb[j], acc[i][j], 0, 0, 0);
    __syncthreads();
  }

  const long row0 = (long)mb * 128 + wr * 64 + ((lane >> 4) << 2);
  const int col0 = nb * 128 + wc * 64 + (lane & 15);
  if (mb >= mbT) {
    const long r0 = row0 - (long)mbT * 128;
#pragma unroll
    for (int i = 0; i < 4; ++i)
#pragma unroll
      for (int j = 0; j < 4; ++j)
#pragma unroll
        for (int r = 0; r < 4; ++r)
          Ct[(long)(col0 + j * 16) * ldct + (r0 + i * 16 + r)] = (CT)acc[i][j][r];
  } else {
#pragma unroll
    for (int i = 0; i < 4; ++i)
#pragma unroll
      for (int j = 0; j < 4; ++j)
#pragma unroll
        for (int r = 0; r < 4; ++r)
          C[(row0 + i * 16 + r) * ldc + (col0 + j * 16)] = (CT)acc[i][j][r];
  }
}

// ---------------------------------------------- split-K partial reduce (4 -> 1)
__global__ __launch_bounds__(256) void k_red4(const float* __restrict__ p,
                                              bf16* __restrict__ out) {
  const int i = blockIdx.x * 256 + threadIdx.x;
  const int SL = 512 * 1024;
  const int b = (i * 4) / SL;
  const int e = (i * 4) % SL;
  const float* base = p + (size_t)b * 4 * SL + e;
  float4 s0 = *reinterpret_cast<const float4*>(base);
  float4 s1 = *reinterpret_cast<const float4*>(base + SL);
  float4 s2 = *reinterpret_cast<const float4*>(base + 2 * SL);
  float4 s3 = *reinterpret_cast<const float4*>(base + 3 * SL);
  bf16x4 o;
  o[0] = (bf16)(s0.x + s1.x + s2.x + s3.x);
  o[1] = (bf16)(s0.y + s1.y + s2.y + s3.y);
  o[2] = (bf16)(s0.z + s1.z + s2.z + s3.z);
  o[3] = (bf16)(s0.w + s1.w + s2.w + s3.w);
  *reinterpret_cast<bf16x4*>(out + (size_t)b * SL + e) = o;
}

// ------------------------------------------------------------- fused attention
// grid (64 lt, 16 h, 4 b), 256 thr = 4 waves x 16 q-rows.  LDS 64KB:
//   Ks [256 perm-rows][64 d] swz (32K) | Vs = V^T [64 d][256 k] swz (32K)
// Swapped QK^T (mfma(K,Q)) -> lane&15 = q-row holds all 256 keys across the
// 4 lane-groups; K rows permuted (key 32ks+8g+2t+b -> row 32ks+16b+4g+t) so
// the PV A-fragment packs IN-LANE: pa[2t]=p[2ks][t], pa[2t+1]=p[2ks+1][t].
// No P LDS round-trip, 2 shfl_xor softmax, deferred 1/sum normalization.
__global__ __launch_bounds__(256) void k_attn(const bf16* __restrict__ q,
                                              const bf16* __restrict__ kc,
                                              const bf16* __restrict__ vT,
                                              bf16* __restrict__ aout) {
  const int lt = blockIdx.x, h = blockIdx.y, b = blockIdx.z;
  const int tid = threadIdx.x, lane = tid & 63, wid = tid >> 6;
  const int x = lane & 15, g = lane >> 4;
  __shared__ bf16 smem[32768];  // 64 KB
  bf16* Ks = smem;
  bf16* Vs = smem + 16384;

  // stage K with permuted rows
  const bf16* kb = kc + ((long)b * 256) * 1024 + h * 64;
#pragma unroll
  for (int it = 0; it < 8; ++it) {
    const int lin = it * 256 + tid;
    const int k = lin >> 3, s = lin & 7;
    const int rel = k & 31;
    const int pk = (k & ~31) | ((rel & 1) << 4) | ((rel >> 3) << 2) | ((rel >> 1) & 3);
    bf16x8 v = *reinterpret_cast<const bf16x8*>(kb + (long)k * 1024 + s * 8);
    *reinterpret_cast<bf16x8*>(reinterpret_cast<char*>(Ks) + pk * 128 +
                               ((s ^ (pk & 7)) << 4)) = v;
  }
  // stage V^T [64 d][256 k], vectorized
  const bf16* vb = vT + (long)b * 1024 * 256 + (long)h * 64 * 256;
#pragma unroll
  for (int it = 0; it < 8; ++it) {
    const int lin = it * 256 + tid;
    const int d = lin >> 5, s = lin & 31;
    bf16x8 v = *reinterpret_cast<const bf16x8*>(vb + (long)d * 256 + s * 8);
    *reinterpret_cast<bf16x8*>(reinterpret_cast<char*>(Vs) + d * 512 +
                               ((s ^ (d & 7)) << 4)) = v;
  }

  // Q fragments (global, before the barrier): row = this wave's q-row x
  const long qrow0 = (long)b * 4096 + lt * 64 + wid * 16;
  const bf16* qb = q + (qrow0 + x) * 1024 + h * 64;
  bf16x8 qf[2];
#pragma unroll
  for (int ks2 = 0; ks2 < 2; ++ks2)
    qf[ks2] = *reinterpret_cast<const bf16x8*>(qb + ks2 * 32 + g * 8);

  __syncthreads();

  // swapped QK^T: ln[f] = S^T tile; lane holds q-row x, keys pi^-1(16f+4g+r)
  f32x4 ln[16] = {};
#pragma unroll
  for (int ks2 = 0; ks2 < 2; ++ks2) {
    const int slot = ks2 * 4 + g;
#pragma unroll
    for (int f = 0; f < 16; ++f) {
      const int row = f * 16 + x;
      bf16x8 kf = *reinterpret_cast<const bf16x8*>(
          reinterpret_cast<const char*>(Ks) + row * 128 + ((slot ^ (row & 7)) << 4));
      ln[f] = __builtin_amdgcn_mfma_f32_16x16x32_bf16(kf, qf[ks2], ln[f], 0, 0, 0);
    }
  }

  // in-register softmax over this lane's 64 keys + 2-shfl cross-group combine
  float m = -1e30f;
#pragma unroll
  for (int f = 0; f < 16; ++f)
#pragma unroll
    for (int r = 0; r < 4; ++r) m = fmaxf(m, ln[f][r]);
  m = fmaxf(m, __shfl_xor(m, 16, 64));
  m = fmaxf(m, __shfl_xor(m, 32, 64));
  float sum = 0.f;
#pragma unroll
  for (int f = 0; f < 16; ++f)
#pragma unroll
    for (int r = 0; r < 4; ++r) {
      const float p = __expf((ln[f][r] - m) * 0.125f);
      ln[f][r] = p;
      sum += p;
    }
  sum += __shfl_xor(sum, 16, 64);
  sum += __shfl_xor(sum, 32, 64);
  const float inv = 1.f / sum;

  // PV: A = unnormalized P packed in-lane, B = V^T from LDS
  f32x4 oacc[4] = {};
#pragma unroll
  for (int ks = 0; ks < 8; ++ks) {
    bf16x8 pa;
#pragma unroll
    for (int t = 0; t < 4; ++t) {
      pa[2 * t] = (bf16)ln[2 * ks][t];
      pa[2 * t + 1] = (bf16)ln[2 * ks + 1][t];
    }
    const int slot = ks * 4 + g;
#pragma unroll
    for (int nf = 0; nf < 4; ++nf) {
      const int d2 = nf * 16 + x;
      bf16x8 vv = *reinterpret_cast<const bf16x8*>(
          reinterpret_cast<const char*>(Vs) + d2 * 512 + ((slot ^ (d2 & 7)) << 4));
      oacc[nf] = __builtin_amdgcn_mfma_f32_16x16x32_bf16(pa, vv, oacc[nf], 0, 0, 0);
    }
  }

  // epilogue: lane (x,g) reg r holds out[q-row 4g+r][d = x+16nf]; normalize
  float invr[4];
#pragma unroll
  for (int r = 0; r < 4; ++r) invr[r] = __shfl(inv, 4 * g + r, 64);
  bf16* ob = aout + (qrow0 + 4 * g) * 1024 + h * 64 + x;
#pragma unroll
  for (int nf = 0; nf < 4; ++nf)
#pragma unroll
    for (int r = 0; r < 4; ++r)
      ob[(long)r * 1024 + nf * 16] = (bf16)(oacc[nf][r] * invr[r]);
}

// --------------------------------------------------------------------- launch
extern "C" void kernel_launch(void* const* d_in, const int* in_sizes, int n_in,
                              void* d_out, int out_size, void* d_ws, size_t ws_size,
                              hipStream_t stream) {
  const float* x  = (const float*)d_in[0];
  const float* Wq = (const float*)d_in[1];
  const float* Wk = (const float*)d_in[2];
  const float* Wv = (const float*)d_in[3];
  const float* Wo = (const float*)d_in[4];
  const float* Pk = (const float*)d_in[5];
  const float* Pv = (const float*)d_in[6];
  char* ws = (char*)d_ws;
  const long MB = 1024L * 1024;
  bf16* xbf = (bf16*)ws;               // 32 MB (dead after Q gemm -> aout)
  bf16* XT  = (bf16*)(ws + 32 * MB);   // 32 MB x^T per batch
  bf16* WqT = (bf16*)(ws + 64 * MB);
  bf16* WkT = (bf16*)(ws + 66 * MB);
  bf16* WvT = (bf16*)(ws + 68 * MB);
  bf16* WoT = (bf16*)(ws + 70 * MB);
  bf16* PT  = (bf16*)(ws + 72 * MB);   // [Pk^T ; Pv^T] = [512][4096]
  float* XCp = (float*)(ws + 76 * MB); // 32 MB fp32 split-K partials
  bf16* qbf = (bf16*)(ws + 76 * MB);   // 32 MB (after reduce)
  bf16* XC  = (bf16*)(ws + 108 * MB);  // 4 MB [4][512][1024]
  bf16* kcb = (bf16*)(ws + 112 * MB);  // 2 MB [4][256][1024]
  bf16* vcT = (bf16*)(ws + 114 * MB);  // 2 MB [4][1024][256]
  bf16* aout = xbf;
  const int BIG = 1 << 30;
  (void)in_sizes; (void)n_in; (void)out_size; (void)ws_size;

  // 1) x -> xbf (bf16) and XT (x^T per batch), one pass
  k_castT<<<dim3(16, 64, 4), 256, 0, stream>>>(x, xbf, XT);

  // 2) W transposes
  TP4 tw = {{Wq, Wk, Wv, Wo}, {WqT, WkT, WvT, WoT}};
  k_tcast<<<dim3(16, 16, 4), 256, 0, stream>>>(tw, 1024, 1024);

  // 3) P transposes
  TP4 tp = {{Pk, Pv, Pk, Pk}, {PT, PT + 256 * 4096, PT, PT}};
  k_tcast<<<dim3(4, 64, 2), 256, 0, stream>>>(tp, 4096, 256);

  // 4) XC split-K partials + reduce
  k_gemm_nt<float><<<dim3(4, 8, 16), 256, 0, stream>>>(
      PT, XT, XT, XCp, 4096, 4096, 1024, 1024, 0, 1024L * 4096, 512L * 1024, 4, 1024,
      BIG, XCp, 0, 1024, BIG);
  k_red4<<<dim3(2048), 256, 0, stream>>>(XCp, XC);

  // 5) kc = XCk@Wk (normal) ; vcT = (XCv@Wv)^T (transposed epilogue)
  k_gemm_nt<bf16><<<dim3(4, 8, 4), 256, 0, stream>>>(
      XC, WkT, WvT, kcb, 1024, 1024, 1024, 1024, 512L * 1024, 0, 256L * 1024, 1, 0, 2,
      vcT, 1024L * 256, 256, 2);

  // 6) Q = x @ Wq
  k_gemm_nt<bf16><<<dim3(128, 8, 1), 256, 0, stream>>>(
      xbf, WqT, WqT, qbf, 1024, 1024, 1024, 1024, 0, 0, 0, 1, 0, BIG, qbf, 0, 1024,
      BIG);

  // 7) attention
  k_attn<<<dim3(64, 16, 4), 256, 0, stream>>>(qbf, kcb, vcT, aout);

  // 8) out = aout @ Wo (fp32 out)
  k_gemm_nt<float><<<dim3(128, 8, 1), 256, 0, stream>>>(
      aout, WoT, WoT, (float*)d_out, 1024, 1024, 1024, 1024, 0, 0, 0, 1, 0, BIG,
      (float*)d_out, 0, 1024, BIG);
}